// Round 1
// 477.201 us; speedup vs baseline: 1.0484x; 1.0484x over previous
//
#include <hip/hip_runtime.h>
#include <math.h>

namespace {

typedef short short8 __attribute__((ext_vector_type(8)));
typedef float f32x4 __attribute__((ext_vector_type(4)));

constexpr int kB = 4, kT = 2048, kD = 512, kE = 4, kC = 1024, kHE = 512,
              kO = 512, kEC = 4096;

__device__ __forceinline__ unsigned short f2bf(float f) {
    unsigned int u = __float_as_uint(f);
    u += 0x7fffu + ((u >> 16) & 1u);   // RNE
    return (unsigned short)(u >> 16);
}

__device__ __forceinline__ float gelu_exact(float v) {
    return 0.5f * v * (1.0f + erff(v * 0.70710678118654752f));
}

#define GLDS16(g, l)                                                      \
    __builtin_amdgcn_global_load_lds(                                     \
        (const __attribute__((address_space(1))) unsigned int*)(g),       \
        (__attribute__((address_space(3))) unsigned int*)(l), 16, 0, 0)

// ---------------------------------------------------------------------------
// Batched transpose+cast: in[z] is R x Cc fp32 -> out[z] is Cc x R bf16.
__global__ __launch_bounds__(256)
void transpose_cast(const float* __restrict__ in, unsigned short* __restrict__ out,
                    int R, int Cc, long long sIn, long long sOut)
{
    __shared__ float tile[32][33];
    const int z = blockIdx.z;
    const float* ip = in + (long long)z * sIn;
    unsigned short* op = out + (long long)z * sOut;
    const int c0 = blockIdx.x * 32, r0 = blockIdx.y * 32;
    const int tx = threadIdx.x & 31, ty = threadIdx.x >> 5;  // ty 0..7
#pragma unroll
    for (int i = 0; i < 4; ++i) {
        const int r = ty + i * 8;
        tile[r][tx] = ip[(size_t)(r0 + r) * Cc + c0 + tx];
    }
    __syncthreads();
#pragma unroll
    for (int i = 0; i < 4; ++i) {
        const int c = ty + i * 8;
        op[(size_t)(c0 + c) * R + r0 + tx] = f2bf(tile[tx][c]);
    }
}

// Plain elementwise fp32 -> bf16 (n multiple of 4).
__global__ __launch_bounds__(256)
void cast_bf16(const float* __restrict__ in, unsigned short* __restrict__ out,
               long long n)
{
    const long long i = ((long long)blockIdx.x * blockDim.x + threadIdx.x) * 4;
    if (i < n) {
        const float4 v = *(const float4*)&in[i];
        unsigned short o[4] = {f2bf(v.x), f2bf(v.y), f2bf(v.z), f2bf(v.w)};
        *(uint2*)&out[i] = *(const uint2*)o;
    }
}

// ---------------------------------------------------------------------------
// MFMA GEMM: C[z] = A[z%zModA] (MxK, k-contig) * B[z%zModB]^T (NxK, k-contig)
// B element (n,k) at ((k>>bShift)*N + n)<<bShift | (k & mask).
// MODE: 0 = bf16 store, 1 = bf16 store of gelu(acc+bias[n]), 3 = f32 acc+bias[n].
//
// This revision vs the 500 µs baseline:
//  * double-buffered LDS (2x32KB) with counted s_waitcnt vmcnt(8) prefetch:
//    next K-tile's 8 global_load_lds stay in flight across the barrier while
//    the current tile's MFMAs run — hides HBM latency at 1-2 blocks/CU.
//  * T2 XOR swizzle: LDS 16B-slot index ^= (row&7). Applied on the GLOBAL
//    source address (GLDS writes linearly, rule #21) and on the ds_read side.
//    Kills the 16-way bank conflict of the stride-128B rows (12.6M conflict
//    cycles/dispatch -> ~0).
template <int MODE>
__global__ __launch_bounds__(256, 2)
void mfma_gemm(const unsigned short* __restrict__ Aall,
               const unsigned short* __restrict__ Ball,
               const float* __restrict__ biasAll,
               void* __restrict__ Call,
               int M, int N, int K,
               long long sA, long long sB, long long sC,
               int zModA, int zModB, int zModBias, int biasStride, int bShift)
{
    __shared__ unsigned short As[2][128 * 64];
    __shared__ unsigned short Bs[2][128 * 64];

    const int z = blockIdx.z;
    const unsigned short* Ab = Aall + (long long)(z % zModA) * sA;
    const unsigned short* Bb = Ball + (long long)(z % zModB) * sB;
    const float* bias =
        (MODE != 0) ? biasAll + (long long)(z % zModBias) * biasStride : nullptr;

    const int t = threadIdx.x;
    const int lane = t & 63;
    const int w = t >> 6;           // wave 0..3
    const int wrow = w * 32;        // staging row block per wave
    const int l8r = lane >> 3;      // 0..7  (row within 8-row staging group)
    // swizzled k element offset: slot (lane&7) in LDS holds global slot
    // ((lane&7) ^ (row&7)); row&7 == l8r for every staged row group.
    const int l8c = ((lane & 7) ^ l8r) * 8;
    const int row0 = blockIdx.y * 128;
    const int col0 = blockIdx.x * 128;

    const int wm = (w >> 1) * 64;   // wave's 64x64 quadrant
    const int wn = (w & 1) * 64;
    const int fr = lane & 15;       // fragment row/col within 16
    const int fq = (lane >> 4) * 8; // fragment k offset
    const int fsw = (fr & 7) * 8;   // read-side swizzle XOR (row&7 == fr&7)

    const unsigned int bMask = (1u << bShift) - 1u;

    f32x4 acc[4][4] = {};

#define STAGE(buf, k0)                                                        \
    do {                                                                      \
        _Pragma("unroll")                                                     \
        for (int r = 0; r < 4; ++r) {                                         \
            const int ar = row0 + wrow + r * 8 + l8r;                         \
            GLDS16(Ab + (size_t)ar * K + ((k0) + l8c),                        \
                   &As[buf][(wrow + r * 8) * 64]);                            \
            const int bn = col0 + wrow + r * 8 + l8r;                         \
            const int gk = (k0) + l8c;                                        \
            const size_t boff =                                               \
                (((size_t)(gk >> bShift) * N + bn) << bShift) + (gk & bMask); \
            GLDS16(Bb + boff, &Bs[buf][(wrow + r * 8) * 64]);                 \
        }                                                                     \
    } while (0)

    const int nt = K / 64;
    STAGE(0, 0);
    int cur = 0;
    for (int t0 = 0; t0 < nt; ++t0) {
        if (t0 + 1 < nt) {
            STAGE(cur ^ 1, (t0 + 1) * 64);
            // wait only for the CURRENT tile's 8 loads; the 8 just issued
            // stay in flight under this iteration's MFMAs.
            asm volatile("s_waitcnt vmcnt(8)" ::: "memory");
        } else {
            asm volatile("s_waitcnt vmcnt(0)" ::: "memory");
        }
        __builtin_amdgcn_s_barrier();   // buf[cur] fully populated, all waves
#pragma unroll
        for (int kk = 0; kk < 2; ++kk) {
            short8 af[4], bf[4];
#pragma unroll
            for (int i = 0; i < 4; ++i)
                af[i] = *(const short8*)&As[cur][(wm + i * 16 + fr) * 64 +
                                                 ((kk * 32 + fq) ^ fsw)];
#pragma unroll
            for (int j = 0; j < 4; ++j)
                bf[j] = *(const short8*)&Bs[cur][(wn + j * 16 + fr) * 64 +
                                                 ((kk * 32 + fq) ^ fsw)];
#pragma unroll
            for (int i = 0; i < 4; ++i)
#pragma unroll
                for (int j = 0; j < 4; ++j)
                    acc[i][j] = __builtin_amdgcn_mfma_f32_16x16x32_bf16(
                        af[i], bf[j], acc[i][j], 0, 0, 0);
        }
        // all ds_reads of buf[cur] drained before anyone overwrites it
        asm volatile("s_waitcnt lgkmcnt(0)" ::: "memory");
        __builtin_amdgcn_sched_barrier(0);
        __builtin_amdgcn_s_barrier();
        cur ^= 1;
    }
#undef STAGE

    // Epilogue. C/D layout: col = lane&15, row = (lane>>4)*4 + reg  [m89/m91].
    const long long cz = (long long)z * sC;
#pragma unroll
    for (int i = 0; i < 4; ++i) {
        const int rowb = row0 + wm + i * 16 + (lane >> 4) * 4;
#pragma unroll
        for (int j = 0; j < 4; ++j) {
            const int col = col0 + wn + j * 16 + fr;
            const float bv = (MODE != 0) ? bias[col] : 0.0f;
#pragma unroll
            for (int r = 0; r < 4; ++r) {
                const float v = acc[i][j][r];
                const size_t idx = (size_t)cz + (size_t)(rowb + r) * N + col;
                if (MODE == 0)
                    ((unsigned short*)Call)[idx] = f2bf(v);
                else if (MODE == 1)
                    ((unsigned short*)Call)[idx] = f2bf(gelu_exact(v + bv));
                else
                    ((float*)Call)[idx] = v + bv;
            }
        }
    }
}

}  // namespace

extern "C" void kernel_launch(void* const* d_in, const int* in_sizes, int n_in,
                              void* d_out, int out_size, void* d_ws, size_t ws_size,
                              hipStream_t stream)
{
    const float* x    = (const float*)d_in[0];  // (B,T,D)
    const float* mask = (const float*)d_in[1];  // (B,T,EC)
    const float* comb = (const float*)d_in[2];  // (B,T,EC)
    const float* w1   = (const float*)d_in[3];  // (E,D,HE)
    const float* b1   = (const float*)d_in[4];  // (E,HE)
    const float* w2   = (const float*)d_in[5];  // (E,HE,O)
    const float* b2   = (const float*)d_in[6];  // (O,)
    float* out = (float*)d_out;                 // (B,T,O) fp32

    // Workspace (bf16 elements): 108 MB total.
    unsigned short* ws    = (unsigned short*)d_ws;
    unsigned short* regA  = ws;                  // 33,554,432: maskT, then combB
    unsigned short* xT    = regA + 33554432;     //  4,194,304: [B][D][T]
    unsigned short* w1T   = xT + 4194304;        //  1,048,576: [E][HE][D]
    unsigned short* w2T   = w1T + 1048576;       //  1,048,576: [E][O][HE]
    unsigned short* xd    = w2T + 1048576;       //  8,388,608: [B][EC][D]; reused as yT [B][E][O][C]
    unsigned short* h     = xd + 8388608;        //  8,388,608: [B*E][C][HE]
    unsigned short* maskT = regA;                // [B][EC][T]
    unsigned short* combB = regA;                // [B][T][EC]
    unsigned short* yT    = xd;

    dim3 blk(256);

    // --- conversions ---
    transpose_cast<<<dim3(kEC / 32, kT / 32, kB), blk, 0, stream>>>(
        mask, maskT, kT, kEC, (long long)kT * kEC, (long long)kT * kEC);
    transpose_cast<<<dim3(kD / 32, kT / 32, kB), blk, 0, stream>>>(
        x, xT, kT, kD, (long long)kT * kD, (long long)kT * kD);
    transpose_cast<<<dim3(kHE / 32, kD / 32, kE), blk, 0, stream>>>(
        w1, w1T, kD, kHE, (long long)kD * kHE, (long long)kD * kHE);
    transpose_cast<<<dim3(kO / 32, kHE / 32, kE), blk, 0, stream>>>(
        w2, w2T, kHE, kO, (long long)kHE * kO, (long long)kHE * kO);

    // --- stage 1: xd[b][ec][d] = sum_t maskT[b][ec][t] * xT[b][d][t] ---
    mfma_gemm<0><<<dim3(kD / 128, kEC / 128, kB), blk, 0, stream>>>(
        maskT, xT, nullptr, xd, kEC, kD, kT,
        (long long)kEC * kT, (long long)kD * kT, (long long)kEC * kD,
        kB, kB, 1, 0, 11);

    // comb cast (after stage 1 — reuses maskT's region, stream-ordered)
    cast_bf16<<<dim3(33554432 / 4 / 256), blk, 0, stream>>>(
        comb, combB, 33554432LL);

    // --- stage 2: h[g][c][he] = gelu(xd[g]*w1T[e]^T + b1[e]) ---
    mfma_gemm<1><<<dim3(kHE / 128, kC / 128, kB * kE), blk, 0, stream>>>(
        xd, w1T, b1, h, kC, kHE, kD,
        (long long)kC * kD, (long long)kHE * kD, (long long)kC * kHE,
        kB * kE, kE, kE, kHE, 9);

    // --- stage 3 (swapped): yT[g][o][c] = w2T[e]*h[g]^T ---
    mfma_gemm<0><<<dim3(kC / 128, kO / 128, kB * kE), blk, 0, stream>>>(
        w2T, h, nullptr, yT, kO, kC, kHE,
        (long long)kO * kHE, (long long)kC * kHE, (long long)kO * kC,
        kE, kB * kE, 1, 0, 9);

    // --- stage 4: out[b][t][o] = sum_ec combB[b][t][ec]*yT[b][e][o][c] + b2 ---
    mfma_gemm<3><<<dim3(kO / 128, kT / 128, kB), blk, 0, stream>>>(
        combB, yT, b2, out, kT, kO, kEC,
        (long long)kT * kEC, (long long)kE * kO * kC, (long long)kT * kO,
        kB, kB, 1, 0, 10);
}